// Round 11
// baseline (23335.329 us; speedup 1.0000x reference)
//
#include <hip/hip_runtime.h>
#include <math.h>

#define B_ 16
#define N_ 2048
#define M_ 2048
#define ITERS_ 100
#define RCH_ 64
#define NCH_ (N_ / RCH_)            // 32 chunks
// (1/eps)*log2(e), eps = 0.1
#define SCALE_ 14.426950408889634f
// u16 fixed-point C: Chat = c16/65535
#define KQ_ (SCALE_ / 65535.0f)

typedef float f4 __attribute__((ext_vector_type(4)));
typedef unsigned short u16x8 __attribute__((ext_vector_type(8)));

static __device__ __forceinline__ f4 exp2v(f4 x) {
  return f4{exp2f(x.x), exp2f(x.y), exp2f(x.z), exp2f(x.w)};
}
static __device__ __forceinline__ float hsum(f4 x) {
  return (x.x + x.y) + (x.z + x.w);
}

__global__ __launch_bounds__(256) void init_kernel(float* __restrict__ lF) {
  lF[blockIdx.x * 256 + threadIdx.x] = 0.f;
}

// One fused Sinkhorn iteration (log-domain factorized, R4-proven):
//   g[n] = p'[n] / rowsum_n,  rowsum_n = sum_m 2^(lF[m] - SCALE_*C[n,m])
//   psum[s][b][m] = sum_{n in chunk s} g[n]*2^(lF[m]-SCALE_*C[n,m])  (F-weighted)
// V=0: first iter — exact fp32 C (NT loads), lF=0, persists u16 T.
// V=1: hot iters — u16 T stream with an explicit 4-row register pipeline
//      (12 outstanding 16B loads/wave) to cover memory latency at 2 blk/CU.
// V=2: last iter — exact fp32 C, writes g_out.
// Block (b,s): rows [s*64,s*64+64); 4 waves x 16 rows; lane owns cols
// {k*512 + 8*lane + j : k=0..3, j=0..7}.
template <int V>
__global__ __launch_bounds__(256, 2) void sink_iter(
    const float* __restrict__ C, unsigned short* __restrict__ T,
    const float* __restrict__ p, const float* __restrict__ lF_arr,
    float* __restrict__ psum, float* __restrict__ g_out) {
  __shared__ float lds[4][M_];  // 32 KB
  const int tid = threadIdx.x;
  const int lane = tid & 63, w = tid >> 6;
  const int bid = blockIdx.x;
  const int b = bid >> 5, s = bid & (NCH_ - 1);

  f4 lF[8];
  if (V == 0) {
#pragma unroll
    for (int k = 0; k < 8; k++) lF[k] = f4{0.f, 0.f, 0.f, 0.f};
  } else {
    const f4* L = (const f4*)(lF_arr + (size_t)b * M_);
#pragma unroll
    for (int k = 0; k < 4; k++) {
      lF[2 * k] = L[k * 128 + 2 * lane];
      lF[2 * k + 1] = L[k * 128 + 2 * lane + 1];
    }
  }

  f4 sr[8];
#pragma unroll
  for (int k = 0; k < 8; k++) sr[k] = f4{0.f, 0.f, 0.f, 0.f};

  const int row0 = s * RCH_ + w * 16;
  const float* prow = p + (size_t)b * N_ + row0;

  if (V == 1) {
    const u16x8* Trb =
        (const u16x8*)(T + ((size_t)b * N_ + row0) * (size_t)M_);
    // 4-row register pipeline, statically named (no runtime indexing)
    u16x8 tb0[4], tb1[4], tb2[4], tb3[4];
#define PREF_(dst, r)                                        \
  {                                                          \
    _Pragma("unroll") for (int k = 0; k < 4; k++)            \
        dst[k] = Trb[(r) * 256 + k * 64 + lane];             \
  }
    PREF_(tb0, 0)
    PREF_(tb1, 1)
    PREF_(tb2, 2)

    auto step = [&](u16x8 (&tt)[4], int i) {
      f4 e[8];
      float rs = 0.f;
#pragma unroll
      for (int k = 0; k < 4; k++) {
        u16x8 t = tt[k];
        f4 x0 = lF[2 * k] -
                KQ_ * f4{(float)t[0], (float)t[1], (float)t[2], (float)t[3]};
        f4 x1 = lF[2 * k + 1] -
                KQ_ * f4{(float)t[4], (float)t[5], (float)t[6], (float)t[7]};
        e[2 * k] = exp2v(x0);
        e[2 * k + 1] = exp2v(x1);
        rs += hsum(e[2 * k]) + hsum(e[2 * k + 1]);
      }
#pragma unroll
      for (int o = 32; o; o >>= 1) rs += __shfl_xor(rs, o, 64);
      float g = (prow[i] + 1e-8f) / rs;
#pragma unroll
      for (int k = 0; k < 8; k++) sr[k] += e[k] * g;
    };

#pragma unroll
    for (int i = 0; i < 16; i++) {
      const int pf = i + 3;
      if (pf < 16) {
        if ((pf & 3) == 0) PREF_(tb0, pf)
        else if ((pf & 3) == 1) PREF_(tb1, pf)
        else if ((pf & 3) == 2) PREF_(tb2, pf)
        else PREF_(tb3, pf)
      }
      if ((i & 3) == 0) step(tb0, i);
      else if ((i & 3) == 1) step(tb1, i);
      else if ((i & 3) == 2) step(tb2, i);
      else step(tb3, i);
    }
#undef PREF_
  } else {
#pragma unroll 2
    for (int i = 0; i < 16; i++) {
      const size_t roff = ((size_t)b * N_ + row0 + i) * (size_t)M_;
      f4 e[8];
      float rs = 0.f;
      const f4* Cr = (const f4*)(C + roff);
#pragma unroll
      for (int k = 0; k < 4; k++) {
        f4 c0 = __builtin_nontemporal_load(&Cr[k * 128 + 2 * lane]);
        f4 c1 = __builtin_nontemporal_load(&Cr[k * 128 + 2 * lane + 1]);
        if (V == 0) {  // persist u16 T for hot iterations
          u16x8 o;
          o[0] = (unsigned short)rintf(c0.x * 65535.f);
          o[1] = (unsigned short)rintf(c0.y * 65535.f);
          o[2] = (unsigned short)rintf(c0.z * 65535.f);
          o[3] = (unsigned short)rintf(c0.w * 65535.f);
          o[4] = (unsigned short)rintf(c1.x * 65535.f);
          o[5] = (unsigned short)rintf(c1.y * 65535.f);
          o[6] = (unsigned short)rintf(c1.z * 65535.f);
          o[7] = (unsigned short)rintf(c1.w * 65535.f);
          ((u16x8*)(T + roff))[k * 64 + lane] = o;
        }
        e[2 * k] = exp2v(lF[2 * k] - SCALE_ * c0);
        e[2 * k + 1] = exp2v(lF[2 * k + 1] - SCALE_ * c1);
        rs += hsum(e[2 * k]) + hsum(e[2 * k + 1]);
      }
#pragma unroll
      for (int o = 32; o; o >>= 1) rs += __shfl_xor(rs, o, 64);
      float g = (prow[i] + 1e-8f) / rs;
      if (V == 2 && lane == 0) g_out[(size_t)b * N_ + row0 + i] = g;
#pragma unroll
      for (int k = 0; k < 8; k++) sr[k] += e[k] * g;
    }
  }

  // cross-wave column reduction -> psum (F-weighted colsums)
#pragma unroll
  for (int k = 0; k < 4; k++) {
    *(f4*)&lds[w][k * 512 + 8 * lane] = sr[2 * k];
    *(f4*)&lds[w][k * 512 + 8 * lane + 4] = sr[2 * k + 1];
  }
  __syncthreads();
  {
    const int base = w * 512 + 8 * lane;
    f4 a0 = *(const f4*)&lds[0][base] + *(const f4*)&lds[1][base] +
            *(const f4*)&lds[2][base] + *(const f4*)&lds[3][base];
    f4 a1 = *(const f4*)&lds[0][base + 4] + *(const f4*)&lds[1][base + 4] +
            *(const f4*)&lds[2][base + 4] + *(const f4*)&lds[3][base + 4];
    float* po = &psum[(size_t)(s * B_ + b) * M_ + base];
    *(f4*)po = a0;
    *(f4*)(po + 4) = a1;
  }
}

// lF update (log-domain, multiplicative — psum includes F):
//   lF_new = lF_old + log2(q' / sum_s psum)
__global__ __launch_bounds__(256) void lfk_kernel(
    const float* __restrict__ psum, const float* __restrict__ q,
    float* __restrict__ lF) {
  int gid = blockIdx.x * 256 + threadIdx.x;  // b*M_ + m
  int b = gid >> 11;
  int m = gid & (M_ - 1);
  float S = 0.f;
#pragma unroll 8
  for (int s = 0; s < NCH_; s++)
    S += psum[(size_t)(s * B_ + b) * M_ + m];
  lF[gid] += log2f((q[gid] + 1e-8f) / S);
}

// pi = g[n] * 2^(lF[m] - SCALE_*C)  (exact fp32 C)
__global__ __launch_bounds__(256) void pi_kernel(
    const float* __restrict__ C, const float* __restrict__ g_arr,
    const float* __restrict__ lF_arr, float* __restrict__ out) {
  int bid = blockIdx.x;
  int tid = threadIdx.x;
  int b = bid >> 11;
  float gg = g_arr[bid];
  const f4* Cr = (const f4*)(C + (size_t)bid * M_);
  const f4* Lr = (const f4*)(lF_arr + (size_t)b * M_);
  f4* Or = (f4*)(out + (size_t)bid * M_);
#pragma unroll
  for (int k = 0; k < 2; k++) {
    int i = tid + (k << 8);
    f4 c = __builtin_nontemporal_load(&Cr[i]);
    f4 L = Lr[i];
    f4 r;
    r.x = gg * exp2f(fmaf(-SCALE_, c.x, L.x));
    r.y = gg * exp2f(fmaf(-SCALE_, c.y, L.y));
    r.z = gg * exp2f(fmaf(-SCALE_, c.z, L.z));
    r.w = gg * exp2f(fmaf(-SCALE_, c.w, L.w));
    __builtin_nontemporal_store(r, &Or[i]);
  }
}

extern "C" void kernel_launch(void* const* d_in, const int* in_sizes, int n_in,
                              void* d_out, int out_size, void* d_ws, size_t ws_size,
                              hipStream_t stream) {
  const float* p = (const float*)d_in[0];
  const float* q = (const float*)d_in[1];
  const float* C = (const float*)d_in[2];
  float* out = (float*)d_out;

  const size_t Telems = (size_t)B_ * N_ * M_;     // 67.1M u16 = 134 MB
  const size_t psz = (size_t)NCH_ * B_ * M_;      // 1,048,576 floats = 4 MB
  const size_t gsz = (size_t)B_ * N_;
  const size_t fsz = (size_t)B_ * M_;
  const size_t need_all =
      Telems * sizeof(unsigned short) + (psz + gsz + fsz) * sizeof(float);

  unsigned short* T;
  float *psum, *g_arr, *lF;
  if (ws_size >= need_all) {
    T = (unsigned short*)d_ws;
    psum = (float*)(T + Telems);
    g_arr = psum + psz;
    lF = g_arr + gsz;
  } else {
    // g,lF in ws (256 KB); T in d_out front (134 MB), psum in d_out tail
    // (4 MB). T last read at t=98, psum last read by the final lfk;
    // pi_kernel then rewrites all of d_out reading only C/g/lF -> safe,
    // deterministic (no cross-call state).
    g_arr = (float*)d_ws;
    lF = g_arr + gsz;
    T = (unsigned short*)d_out;
    psum = out + ((size_t)out_size - psz);
  }

  init_kernel<<<(B_ * M_) / 256, 256, 0, stream>>>(lF);

  for (int t = 0; t < ITERS_; ++t) {
    if (t == 0)
      sink_iter<0><<<B_ * NCH_, 256, 0, stream>>>(C, T, p, lF, psum, g_arr);
    else if (t == ITERS_ - 1)
      sink_iter<2><<<B_ * NCH_, 256, 0, stream>>>(C, T, p, lF, psum, g_arr);
    else
      sink_iter<1><<<B_ * NCH_, 256, 0, stream>>>(C, T, p, lF, psum, g_arr);
    lfk_kernel<<<(B_ * M_) / 256, 256, 0, stream>>>(psum, q, lF);
  }
  pi_kernel<<<B_ * N_, 256, 0, stream>>>(C, g_arr, lF, out);
}

// Round 12
// 3482.602 us; speedup vs baseline: 6.7005x; 6.7005x over previous
//
#include <hip/hip_runtime.h>
#include <math.h>

#define B_ 16
#define N_ 2048
#define M_ 2048
#define ITERS_ 100
#define RCH_ 32
#define NCH_ (N_ / RCH_)            // 64 chunks -> 1024 blocks
// (1/eps)*log2(e), eps = 0.1
#define SCALE_ 14.426950408889634f
// u16 fixed-point C: Chat = c16/65535
#define KQ_ (SCALE_ / 65535.0f)

typedef float f4 __attribute__((ext_vector_type(4)));
typedef unsigned short u16x4 __attribute__((ext_vector_type(4)));

static __device__ __forceinline__ float hsum(f4 x) {
  return (x.x + x.y) + (x.z + x.w);
}

__global__ __launch_bounds__(256) void init_kernel(float* __restrict__ lF) {
  lF[blockIdx.x * 256 + threadIdx.x] = 0.f;
}

// One fused Sinkhorn iteration (log-domain factorized — the R4-proven math):
//   g[n] = p'[n] / rowsum_n,  rowsum_n = sum_m 2^(lF[m] - SCALE_*C[n,m])
//   psum[s][b][m] = sum_{n in chunk s} g[n]*2^(lF[m]-SCALE_*C[n,m]) (F-weighted)
// V=0: first iter — exact fp32 C (NT loads), lF=0, persists u16 T (fused conv).
// V=1: hot iters  — u16 T stream (u16x4 8B loads, R4's exact inner loop).
// V=2: last iter  — exact fp32 C, writes g_out.
// Block (b,s): rows [s*32,s*32+32); 4 waves x 8 rows; lane owns cols
// {k*256 + 4*lane + j : k=0..7, j=0..3}.
template <int V>
__global__ __launch_bounds__(256, 2) void sink_iter(
    const float* __restrict__ C, unsigned short* __restrict__ T,
    const float* __restrict__ p, const float* __restrict__ lF_arr,
    float* __restrict__ psum, float* __restrict__ g_out) {
  __shared__ float lds[4][M_];  // 32 KB
  const int tid = threadIdx.x;
  const int lane = tid & 63, w = tid >> 6;
  const int bid = blockIdx.x;
  const int b = bid >> 6, s = bid & (NCH_ - 1);

  f4 lF[8];
  if (V == 0) {
#pragma unroll
    for (int k = 0; k < 8; k++) lF[k] = f4{0.f, 0.f, 0.f, 0.f};
  } else {
    const f4* L = (const f4*)(lF_arr + (size_t)b * M_);
#pragma unroll
    for (int k = 0; k < 8; k++) lF[k] = L[k * 64 + lane];
  }

  f4 sr[8];
#pragma unroll
  for (int k = 0; k < 8; k++) sr[k] = f4{0.f, 0.f, 0.f, 0.f};

  const int row0 = s * RCH_ + w * 8;
  const float* prow = p + (size_t)b * N_ + row0;

#pragma unroll 2
  for (int i = 0; i < 8; i++) {
    const size_t roff = ((size_t)b * N_ + row0 + i) * (size_t)M_;
    f4 e[8];
    float rs = 0.f;
    if (V == 1) {
      const u16x4* Tr = (const u16x4*)(T + roff);
#pragma unroll
      for (int k = 0; k < 8; k++) {
        u16x4 t = Tr[k * 64 + lane];
        f4 x = lF[k] -
               KQ_ * f4{(float)t.x, (float)t.y, (float)t.z, (float)t.w};
        e[k] = f4{exp2f(x.x), exp2f(x.y), exp2f(x.z), exp2f(x.w)};
        rs += hsum(e[k]);
      }
    } else {
      const f4* Cr = (const f4*)(C + roff);
#pragma unroll
      for (int k = 0; k < 8; k++) {
        f4 c = __builtin_nontemporal_load(&Cr[k * 64 + lane]);
        if (V == 0) {  // persist u16 T for hot iterations (fused conv)
          u16x4 o;
          o.x = (unsigned short)rintf(c.x * 65535.f);
          o.y = (unsigned short)rintf(c.y * 65535.f);
          o.z = (unsigned short)rintf(c.z * 65535.f);
          o.w = (unsigned short)rintf(c.w * 65535.f);
          ((u16x4*)(T + roff))[k * 64 + lane] = o;
        }
        f4 x = lF[k] - SCALE_ * c;
        e[k] = f4{exp2f(x.x), exp2f(x.y), exp2f(x.z), exp2f(x.w)};
        rs += hsum(e[k]);
      }
    }
#pragma unroll
    for (int o = 32; o; o >>= 1) rs += __shfl_xor(rs, o, 64);
    float g = (prow[i] + 1e-8f) / rs;
    if (V == 2 && lane == 0) g_out[(size_t)b * N_ + row0 + i] = g;
#pragma unroll
    for (int k = 0; k < 8; k++) sr[k] += e[k] * g;
  }

  // cross-wave column reduction -> psum (F-weighted colsums)
#pragma unroll
  for (int k = 0; k < 8; k++) *(f4*)&lds[w][k * 256 + lane * 4] = sr[k];
  __syncthreads();
#pragma unroll
  for (int k2 = 0; k2 < 2; k2++) {
    int k = w * 2 + k2;
    int ci = k * 256 + lane * 4;
    f4 tot = *(const f4*)&lds[0][ci] + *(const f4*)&lds[1][ci] +
             *(const f4*)&lds[2][ci] + *(const f4*)&lds[3][ci];
    *(f4*)&psum[(size_t)(s * B_ + b) * M_ + ci] = tot;
  }
}

// lF update (log-domain, multiplicative — psum includes F):
//   lF_new = lF_old + log2(q' / sum_s psum)
__global__ __launch_bounds__(256) void lfk_kernel(
    const float* __restrict__ psum, const float* __restrict__ q,
    float* __restrict__ lF) {
  int gid = blockIdx.x * 256 + threadIdx.x;  // b*M_ + m
  int b = gid >> 11;
  int m = gid & (M_ - 1);
  float S = 0.f;
#pragma unroll 8
  for (int s = 0; s < NCH_; s++)
    S += psum[(size_t)(s * B_ + b) * M_ + m];
  lF[gid] += log2f((q[gid] + 1e-8f) / S);
}

// pi = g[n] * 2^(lF[m] - SCALE_*C)  (exact fp32 C)
__global__ __launch_bounds__(256) void pi_kernel(
    const float* __restrict__ C, const float* __restrict__ g_arr,
    const float* __restrict__ lF_arr, float* __restrict__ out) {
  int bid = blockIdx.x;
  int tid = threadIdx.x;
  int b = bid >> 11;
  float gg = g_arr[bid];
  const f4* Cr = (const f4*)(C + (size_t)bid * M_);
  const f4* Lr = (const f4*)(lF_arr + (size_t)b * M_);
  f4* Or = (f4*)(out + (size_t)bid * M_);
#pragma unroll
  for (int k = 0; k < 2; k++) {
    int i = tid + (k << 8);
    f4 c = __builtin_nontemporal_load(&Cr[i]);
    f4 L = Lr[i];
    f4 r;
    r.x = gg * exp2f(fmaf(-SCALE_, c.x, L.x));
    r.y = gg * exp2f(fmaf(-SCALE_, c.y, L.y));
    r.z = gg * exp2f(fmaf(-SCALE_, c.z, L.z));
    r.w = gg * exp2f(fmaf(-SCALE_, c.w, L.w));
    __builtin_nontemporal_store(r, &Or[i]);
  }
}

extern "C" void kernel_launch(void* const* d_in, const int* in_sizes, int n_in,
                              void* d_out, int out_size, void* d_ws, size_t ws_size,
                              hipStream_t stream) {
  const float* p = (const float*)d_in[0];
  const float* q = (const float*)d_in[1];
  const float* C = (const float*)d_in[2];
  float* out = (float*)d_out;

  const size_t Telems = (size_t)B_ * N_ * M_;     // 67.1M u16 = 134 MB
  const size_t psz = (size_t)NCH_ * B_ * M_;      // 2,097,152 floats = 8 MB
  const size_t gsz = (size_t)B_ * N_;
  const size_t fsz = (size_t)B_ * M_;
  const size_t need_all =
      Telems * sizeof(unsigned short) + (psz + gsz + fsz) * sizeof(float);

  unsigned short* T;
  float *psum, *g_arr, *lF;
  if (ws_size >= need_all) {
    T = (unsigned short*)d_ws;
    psum = (float*)(T + Telems);
    g_arr = psum + psz;
    lF = g_arr + gsz;
  } else {
    // g,lF in ws (256 KB); T in d_out front (134 MB), psum in d_out tail
    // (8 MB). T last read at t=98, psum last read by the final lfk;
    // pi_kernel then rewrites all of d_out reading only C/g/lF -> safe,
    // deterministic (no cross-call state).
    g_arr = (float*)d_ws;
    lF = g_arr + gsz;
    T = (unsigned short*)d_out;
    psum = out + ((size_t)out_size - psz);
  }

  init_kernel<<<(B_ * M_) / 256, 256, 0, stream>>>(lF);

  for (int t = 0; t < ITERS_; ++t) {
    if (t == 0)
      sink_iter<0><<<B_ * NCH_, 256, 0, stream>>>(C, T, p, lF, psum, g_arr);
    else if (t == ITERS_ - 1)
      sink_iter<2><<<B_ * NCH_, 256, 0, stream>>>(C, T, p, lF, psum, g_arr);
    else
      sink_iter<1><<<B_ * NCH_, 256, 0, stream>>>(C, T, p, lF, psum, g_arr);
    lfk_kernel<<<(B_ * M_) / 256, 256, 0, stream>>>(psum, q, lF);
  }
  pi_kernel<<<B_ * N_, 256, 0, stream>>>(C, g_arr, lF, out);
}